// Round 10
// baseline (810.940 us; speedup 1.0000x reference)
//
#include <hip/hip_runtime.h>
#include <cstdint>

// ---- problem constants ----
#define H_    2048
#define NQ_   16
#define NKV_  4
#define HD_   128
#define FF_   8192
#define B_    2
#define S_    2048
#define TOK   (B_*S_)            // 4096 tokens
#define QKVN  (H_ + 2*NKV_*HD_)  // 3072 = Q(2048) | K(512) | V(512)
#define KVB   64                 // attention KV tile

typedef __bf16 bf16;
typedef bf16  bf16x8 __attribute__((ext_vector_type(8)));
typedef float f32x4  __attribute__((ext_vector_type(4)));
typedef float f32x16 __attribute__((ext_vector_type(16)));

typedef __attribute__((address_space(1))) void as1_void;
typedef __attribute__((address_space(3))) void as3_void;

__device__ __forceinline__ void gload_lds16(const void* g, void* l) {
    __builtin_amdgcn_global_load_lds((as1_void*)g, (as3_void*)l, 16, 0, 0);
}

// ======================================================================
// Weight convert + transpose: W[K][N] f32 -> Wt[outOff+N][K] bf16
// ======================================================================
__global__ __launch_bounds__(256) void wtrans_kernel(
    const float* __restrict__ W, bf16* __restrict__ Wt, int K, int N, int outOff)
{
    __shared__ float tile[32][33];
    const int n0 = (int)blockIdx.x * 32;
    const int k0 = (int)blockIdx.y * 32;
    const int c  = (int)threadIdx.x & 31;
    const int r  = (int)threadIdx.x >> 5;
#pragma unroll
    for (int i = 0; i < 4; ++i)
        tile[r + i*8][c] = W[(size_t)(k0 + r + i*8) * N + n0 + c];
    __syncthreads();
#pragma unroll
    for (int i = 0; i < 4; ++i)
        Wt[(size_t)(outOff + n0 + r + i*8) * K + k0 + c] = (bf16)tile[c][r + i*8];
}

__global__ void biaspack_kernel(const float* __restrict__ bq, const float* __restrict__ bk,
                                const float* __restrict__ bv, float* __restrict__ out)
{
    const int i = (int)(blockIdx.x * 256 + threadIdx.x);
    out[i] = (i < H_) ? bq[i] : (i < H_ + NKV_*HD_ ? bk[i - H_] : bv[i - H_ - NKV_*HD_]);
}

// ======================================================================
// RMSNorm: x f32 [rows][2048] -> y bf16
// ======================================================================
__global__ __launch_bounds__(256) void rmsnorm_kernel(
    const float* __restrict__ x, const float* __restrict__ g, bf16* __restrict__ y)
{
    const int row = (int)blockIdx.x;
    const int tid = (int)threadIdx.x;
    const float* xr = x + (size_t)row * H_;
    const float4 a = *(const float4*)(xr + tid*8);
    const float4 c = *(const float4*)(xr + tid*8 + 4);
    float ss = a.x*a.x + a.y*a.y + a.z*a.z + a.w*a.w
             + c.x*c.x + c.y*c.y + c.z*c.z + c.w*c.w;
#pragma unroll
    for (int d = 1; d < 64; d <<= 1) ss += __shfl_xor(ss, d);
    __shared__ float red[4];
    if ((tid & 63) == 0) red[tid >> 6] = ss;
    __syncthreads();
    const float inv = rsqrtf((red[0]+red[1]+red[2]+red[3]) * (1.0f/H_) + 1e-6f);
    const float vals[8] = {a.x,a.y,a.z,a.w,c.x,c.y,c.z,c.w};
    const float* gp = g + tid*8;
    bf16x8 outv;
#pragma unroll
    for (int e = 0; e < 8; ++e) outv[e] = (bf16)(vals[e] * inv * gp[e]);
    *(bf16x8*)(y + (size_t)row * H_ + tid*8) = outv;
}

// ======================================================================
// V transpose: qkv[tok][3072] V-slice -> Vt[(b*NKV+kh)*HD + d][S]
// ======================================================================
__global__ __launch_bounds__(256) void vtrans_kernel(
    const bf16* __restrict__ qkv, bf16* __restrict__ Vt)
{
    __shared__ bf16 tile[32][33];
    const int tt = (int)blockIdx.x;
    const int d0 = (int)blockIdx.y * 32;
    const int kh = (int)blockIdx.z;
    const int b  = (tt*32) / S_;
    const int s0 = (tt*32) % S_;
    const int c = (int)threadIdx.x & 31;
    const int r = (int)threadIdx.x >> 5;
#pragma unroll
    for (int i = 0; i < 4; ++i)
        tile[r + i*8][c] = qkv[(size_t)(tt*32 + r + i*8)*QKVN + H_ + NKV_*HD_ + kh*HD_ + d0 + c];
    __syncthreads();
#pragma unroll
    for (int i = 0; i < 4; ++i)
        Vt[((size_t)(b*NKV_ + kh)*HD_ + d0 + r + i*8)*S_ + s0 + c] = tile[c][r + i*8];
}

// ======================================================================
// GEMM v5 — 32x32x16 MFMA, m97-exact single-buffer 2-barrier, 128x128.
// Rounds 4-9: four different schedules with 16x16x32 MFMA all pinned at
// ~210us / 26% MfmaUtil at a hard 2 waves/SIMD (acc 128 AGPR). This
// round changes the constant factors: (1) v_mfma_f32_32x32x16_bf16
// (2382 vs 2075 TF ceiling, 4x fewer instructions -> lower per-wave
// issue pressure); (2) wave tile 64x64 = 2x2 32x32 tiles -> acc only
// 4 x f32x16 = 64 AGPR, ~110 arch VGPR -> 3-4 waves/SIMD headroom;
// (3) LDS 32KB single-buffer -> up to 4-5 blocks/CU; latency hidden by
// inter-block TLP (the m97 recipe), not intra-block pipelining.
// Swizzle (conflict-free for 32x32 frag reads, derived): LDS[row][e] =
// logical[row][e ^ ((row&3)<<4)]; staged via pre-XOR'd source oct
// (octS = (lane&7) ^ (((lane>>3)&3)<<1)); fragment read applies same
// XOR. 64 lanes -> 8 granules x 8 lanes each = all 32 banks uniform.
// C/D layout (m74/m101): col = lane&31, row = (reg&3)+8*(reg>>2)+4*(lane>>5).
// MODE 0: +bias -> bf16. 1: GELU(v+bias) -> bf16. 2: v+bias+resid -> f32.
// 3: raw partial -> bf16 at Cout + z*M*N (split-K; bias in reduce).
// ======================================================================
template<int MODE>
__global__ __launch_bounds__(256) void gemm5_kernel(
    const bf16* __restrict__ A, const bf16* __restrict__ Bt,
    const float* __restrict__ bias, const float* __restrict__ resid,
    void* __restrict__ Cout, int M, int N, int Kf, int Ks)
{
    __shared__ bf16 lA[128*64];   // 16 KB
    __shared__ bf16 lB[128*64];   // 16 KB
    const int tid  = (int)threadIdx.x;
    const int wid  = tid >> 6;         // 0..3
    const int lane = tid & 63;
    const int l31  = lane & 31;
    const int hi   = lane >> 5;        // 0..1 -> k-subgroup
    const int z    = (int)blockIdx.z;
    const int kOff = z * Ks;

    // ---- XCD chunk + 8m x 4n superblock of 32 wgs (L2 locality) ----
    const int gx  = (int)gridDim.x;            // N/128, mult of 4
    const int nwg = gx * (int)gridDim.y;       // mult of 32
    int wg = (int)blockIdx.y * gx + (int)blockIdx.x;
    wg = (wg & 7) * (nwg >> 3) + (wg >> 3);
    const int nsup  = gx >> 2;
    const int chunk = wg >> 5;
    const int cin   = wg & 31;
    const int m0 = ((chunk / nsup) * 8 + (cin >> 2)) * 128;
    const int n0 = ((chunk % nsup) * 4 + (cin & 3)) * 128;

    const int wm = (wid >> 1) * 64;    // wave M offset
    const int wn = (wid & 1) * 64;     // wave N offset

    // ---- staging: wave w covers rows w*32..w*32+31 of each tile;
    // 4 instrs x 8 rows; source oct pre-XOR'd: oct ^= (row&3)<<1.
    const int r8   = lane >> 3;                                 // 0..7
    const int octS = (lane & 7) ^ (((lane >> 3) & 3) << 1);
    const bf16* aS = A  + (size_t)(m0 + wid*32 + r8) * Kf + kOff + octS*8;
    const bf16* bS = Bt + (size_t)(n0 + wid*32 + r8) * Kf + kOff + octS*8;

    const int NT = Ks / 64;

    // fragment read: row in [0,128), kk in [0,4); 16B per lane
    auto rdf = [&](const bf16* base, int row, int kk) -> bf16x8 {
        return *(const bf16x8*)&base[row*64 + ((kk*16 + hi*8) ^ ((row & 3) << 4))];
    };

    f32x16 acc[2][2] = {};

    for (int kt = 0; kt < NT; ++kt) {
        const size_t ka = (size_t)kt * 64;
#pragma unroll
        for (int i = 0; i < 4; ++i) {
            gload_lds16(aS + (size_t)(i*8)*Kf + ka, &lA[(wid*32 + i*8)*64]);
            gload_lds16(bS + (size_t)(i*8)*Kf + ka, &lB[(wid*32 + i*8)*64]);
        }
        __syncthreads();   // compiler drains vmcnt(0) -> tile ready
#pragma unroll
        for (int kk = 0; kk < 4; ++kk) {
            bf16x8 af[2], bfr[2];
#pragma unroll
            for (int mf = 0; mf < 2; ++mf) af[mf]  = rdf(lA, wm + mf*32 + l31, kk);
#pragma unroll
            for (int nf = 0; nf < 2; ++nf) bfr[nf] = rdf(lB, wn + nf*32 + l31, kk);
#pragma unroll
            for (int mf = 0; mf < 2; ++mf)
#pragma unroll
                for (int nf = 0; nf < 2; ++nf)
                    acc[mf][nf] = __builtin_amdgcn_mfma_f32_32x32x16_bf16(
                        af[mf], bfr[nf], acc[mf][nf], 0, 0, 0);
        }
        __syncthreads();   // all reads done before next stage overwrites
    }

    // ---- epilogue: 32x32 C/D layout: col=lane&31, row=(reg&3)+8*(reg>>2)+4*hi
#pragma unroll
    for (int nf = 0; nf < 2; ++nf) {
        const int col = n0 + wn + nf*32 + l31;
        const float bj = (MODE == 3) ? 0.f : bias[col];
#pragma unroll
        for (int mf = 0; mf < 2; ++mf) {
            const int rbase = m0 + wm + mf*32 + 4*hi;
#pragma unroll
            for (int reg = 0; reg < 16; ++reg) {
                const int row = rbase + (reg & 3) + 8*(reg >> 2);
                float v = acc[mf][nf][reg] + bj;
                const size_t idx = (size_t)row * N + col;
                if (MODE == 2) {
                    ((float*)Cout)[idx] = v + resid[idx];
                } else if (MODE == 3) {
                    ((bf16*)Cout)[(size_t)z * M * N + idx] = (bf16)v;
                } else {
                    if (MODE == 1) v = 0.5f * v * (1.0f + erff(v * 0.70710678118654752f));
                    ((bf16*)Cout)[idx] = (bf16)v;
                }
            }
        }
    }
}

// split-K reduce: out = p0 + p1 + bias + resid (f32)
__global__ __launch_bounds__(256) void reduce2_kernel(
    const bf16* __restrict__ part, const float* __restrict__ bias,
    const float* __restrict__ resid, float* __restrict__ out)
{
    const size_t i0 = ((size_t)blockIdx.x * 256 + threadIdx.x) * 8;
    const bf16x8 p0 = *(const bf16x8*)(part + i0);
    const bf16x8 p1 = *(const bf16x8*)(part + (size_t)TOK*H_ + i0);
    const int col = (int)(i0 & (H_ - 1));
    const float4 r0 = *(const float4*)(resid + i0);
    const float4 r1 = *(const float4*)(resid + i0 + 4);
    const float4 b0 = *(const float4*)(bias + col);
    const float4 b1 = *(const float4*)(bias + col + 4);
    float4 o0, o1;
    o0.x = (float)p0[0] + (float)p1[0] + b0.x + r0.x;
    o0.y = (float)p0[1] + (float)p1[1] + b0.y + r0.y;
    o0.z = (float)p0[2] + (float)p1[2] + b0.z + r0.z;
    o0.w = (float)p0[3] + (float)p1[3] + b0.w + r0.w;
    o1.x = (float)p0[4] + (float)p1[4] + b1.x + r1.x;
    o1.y = (float)p0[5] + (float)p1[5] + b1.y + r1.y;
    o1.z = (float)p0[6] + (float)p1[6] + b1.z + r1.z;
    o1.w = (float)p0[7] + (float)p1[7] + b1.w + r1.w;
    *(float4*)(out + i0)     = o0;
    *(float4*)(out + i0 + 4) = o1;
}

// ======================================================================
// Flash attention (causal, GQA rep=4). Grid (S/64, NQ, B), 256 thr.
// ======================================================================
__global__ __launch_bounds__(256) void attn_kernel(
    const bf16* __restrict__ qkv, const bf16* __restrict__ Vt,
    bf16* __restrict__ ctx)
{
    __shared__ bf16 lK[2][KVB*HD_];
    __shared__ bf16 lV[2][HD_*KVB];
    __shared__ bf16 lP[4][16*72];
    const int tid  = (int)threadIdx.x;
    const int wid  = tid >> 6;
    const int lane = tid & 63;
    const int lr   = lane & 15;
    const int lg   = lane >> 4;
    const int qt = (int)gridDim.x - 1 - (int)blockIdx.x;
    const int h = (int)blockIdx.y, b = (int)blockIdx.z;
    const int kh = h >> 2;
    const int qb = qt * 64;
    const int qw = qb + wid * 16;
    const float scale = 0.08838834764831845f;

    const bf16* kB[4];
    const bf16* vB[4];
#pragma unroll
    for (int i = 0; i < 4; ++i) {
        const int kRow = (wid*4 + i)*4 + (lane >> 4);
        const int kCol = ((lane & 15) ^ (kRow & 7)) * 8;
        kB[i] = qkv + (size_t)(b*S_ + kRow)*QKVN + H_ + kh*HD_ + kCol;
        const int vRow = (wid*4 + i)*8 + (lane >> 3);
        const int vCol = ((lane & 7) ^ (vRow & 7)) * 8;
        vB[i] = Vt + ((size_t)(b*NKV_ + kh)*HD_ + vRow)*S_ + vCol;
    }

    bf16x8 qf[4];
    {
        const bf16* qp = qkv + (size_t)(b*S_ + qw + lr)*QKVN + h*HD_ + lg*8;
#pragma unroll
        for (int t = 0; t < 4; ++t) qf[t] = *(const bf16x8*)(qp + t*32);
    }

    f32x4 o[8] = {};
    float mrow[4] = {-__builtin_inff(), -__builtin_inff(), -__builtin_inff(), -__builtin_inff()};
    float lrow[4] = {0.f, 0.f, 0.f, 0.f};
    const int nt = qt + 1;

#pragma unroll
    for (int i = 0; i < 4; ++i) {
        gload_lds16(kB[i], &lK[0][(wid*4 + i)*4*HD_]);
        gload_lds16(vB[i], &lV[0][(wid*4 + i)*8*KVB]);
    }

    int cur = 0;
    for (int t = 0; t < nt; ++t) {
        __syncthreads();
        if (t + 1 < nt) {
            const size_t kAdd = (size_t)(t+1)*KVB*QKVN;
            const size_t vAdd = (size_t)(t+1)*KVB;
#pragma unroll
            for (int i = 0; i < 4; ++i) {
                gload_lds16(kB[i] + kAdd, &lK[cur^1][(wid*4 + i)*4*HD_]);
                gload_lds16(vB[i] + vAdd, &lV[cur^1][(wid*4 + i)*8*KVB]);
            }
        }
        const int kv0 = t * KVB;

        f32x4 s[4] = {};
#pragma unroll
        for (int sub = 0; sub < 4; ++sub) {
            const int krow = sub*16 + lr;
            const bf16* kr = &lK[cur][krow*HD_];
            const int swk = (krow & 7) * 8;
#pragma unroll
            for (int d = 0; d < 4; ++d) {
                const bf16x8 kf = *(const bf16x8*)(kr + ((d*32 + lg*8) ^ swk));
                s[sub] = __builtin_amdgcn_mfma_f32_16x16x32_bf16(qf[d], kf, s[sub], 0, 0, 0);
            }
        }

        float p[4][4], rmax[4];
        if (t == qt) {
#pragma unroll
            for (int rr = 0; rr < 4; ++rr) {
                const int q = qw + lg*4 + rr;
                rmax[rr] = -__builtin_inff();
#pragma unroll
                for (int sub = 0; sub < 4; ++sub) {
                    const int kv = kv0 + sub*16 + lr;
                    const float v = s[sub][rr] * scale;
                    p[sub][rr] = (kv <= q) ? v : -__builtin_inff();
                    rmax[rr] = fmaxf(rmax[rr], p[sub][rr]);
                }
            }
        } else {
#pragma unroll
            for (int rr = 0; rr < 4; ++rr) {
                rmax[rr] = -__builtin_inff();
#pragma unroll
                for (int sub = 0; sub < 4; ++sub) {
                    p[sub][rr] = s[sub][rr] * scale;
                    rmax[rr] = fmaxf(rmax[rr], p[sub][rr]);
                }
            }
        }
#pragma unroll
        for (int d = 1; d < 16; d <<= 1)
#pragma unroll
            for (int rr = 0; rr < 4; ++rr)
                rmax[rr] = fmaxf(rmax[rr], __shfl_xor(rmax[rr], d));

        float fsc[4], rsum[4];
#pragma unroll
        for (int rr = 0; rr < 4; ++rr) {
            const float mn = fmaxf(mrow[rr], rmax[rr]);
            fsc[rr]  = __expf(mrow[rr] - mn);
            mrow[rr] = mn;
            rsum[rr] = 0.f;
#pragma unroll
            for (int sub = 0; sub < 4; ++sub) {
                p[sub][rr] = __expf(p[sub][rr] - mn);
                rsum[rr] += p[sub][rr];
            }
        }
#pragma unroll
        for (int d = 1; d < 16; d <<= 1)
#pragma unroll
            for (int rr = 0; rr < 4; ++rr)
                rsum[rr] += __shfl_xor(rsum[rr], d);
#pragma unroll
        for (int rr = 0; rr < 4; ++rr) lrow[rr] = lrow[rr]*fsc[rr] + rsum[rr];
#pragma unroll
        for (int dch = 0; dch < 8; ++dch)
#pragma unroll
            for (int rr = 0; rr < 4; ++rr) o[dch][rr] *= fsc[rr];

#pragma unroll
        for (int sub = 0; sub < 4; ++sub)
#pragma unroll
            for (int rr = 0; rr < 4; ++rr)
                lP[wid][(lg*4 + rr)*72 + sub*16 + lr] = (bf16)p[sub][rr];
        bf16x8 pfr[2];
#pragma unroll
        for (int kk = 0; kk < 2; ++kk)
            pfr[kk] = *(const bf16x8*)&lP[wid][lr*72 + kk*32 + lg*8];

#pragma unroll
        for (int dch = 0; dch < 8; ++dch) {
            const bf16* vr = &lV[cur][(dch*16 + lr)*KVB];
            const int swv = (lr & 7) * 8;
#pragma unroll
            for (int kk = 0; kk < 2; ++kk) {
                const bf16x8 vf = *(const bf16x8*)(vr + ((kk*32 + lg*8) ^ swv));
                o[dch] = __builtin_amdgcn_mfma_f32_16x16x32_bf16(pfr[kk], vf, o[dch], 0, 0, 0);
            }
        }
        cur ^= 1;
    }

#pragma unroll
    for (int rr = 0; rr < 4; ++rr) {
        const float inv = 1.0f / lrow[rr];
        bf16* cp = ctx + (size_t)(b*S_ + qw + lg*4 + rr) * H_ + h*HD_ + lr;
#pragma unroll
        for (int dch = 0; dch < 8; ++dch)
            cp[dch*16] = (bf16)(o[dch][rr] * inv);
    }
}

// ======================================================================
extern "C" void kernel_launch(void* const* d_in, const int* in_sizes, int n_in,
                              void* d_out, int out_size, void* d_ws, size_t ws_size,
                              hipStream_t stream)
{
    const float* hidden = (const float*)d_in[0];
    const float* Wq = (const float*)d_in[1];
    const float* bq = (const float*)d_in[2];
    const float* Wk = (const float*)d_in[3];
    const float* bk = (const float*)d_in[4];
    const float* Wv = (const float*)d_in[5];
    const float* bv = (const float*)d_in[6];
    const float* Wo = (const float*)d_in[7];
    const float* bo = (const float*)d_in[8];
    const float* W1 = (const float*)d_in[9];
    const float* b1 = (const float*)d_in[10];
    const float* W2 = (const float*)d_in[11];
    const float* b2 = (const float*)d_in[12];
    const float* g1 = (const float*)d_in[13];
    const float* g2 = (const float*)d_in[14];
    float* out = (float*)d_out;

    // d_ws is 256 MiB. vt aliases xn1 (dead after QKV GEMM). FFN2 split-K
    // partials alias w1_t (dead after FFN1; sizes equal). Footprint =
    // 264,253,440 B (proven fit).
    char* p = (char*)d_ws;
    auto alloc = [&](size_t bytes) { char* r = p; p += (bytes + 255) & ~(size_t)255; return r; };
    bf16*  wt_qkv = (bf16*)alloc((size_t)QKVN * H_ * 2);
    bf16*  wo_t   = (bf16*)alloc((size_t)H_ * H_ * 2);
    bf16*  w1_t   = (bf16*)alloc((size_t)FF_ * H_ * 2);
    bf16*  w2_t   = (bf16*)alloc((size_t)H_ * FF_ * 2);
    float* bqkv   = (float*)alloc((size_t)QKVN * 4);
    bf16*  xn1    = (bf16*)alloc((size_t)TOK * H_ * 2);
    bf16*  qkv    = (bf16*)alloc((size_t)TOK * QKVN * 2);
    bf16*  ctxb   = (bf16*)alloc((size_t)TOK * H_ * 2);
    float* x1     = (float*)alloc((size_t)TOK * H_ * 4);
    bf16*  xn2    = (bf16*)alloc((size_t)TOK * H_ * 2);
    bf16*  ffn    = (bf16*)alloc((size_t)TOK * FF_ * 2);
    bf16*  vt     = xn1;    // alias (xn1 dead after QKV GEMM)
    bf16*  fpart  = w1_t;   // alias (w1_t dead after FFN1)

    const dim3 blk(256);
    biaspack_kernel<<<dim3(QKVN/256), blk, 0, stream>>>(bq, bk, bv, bqkv);
    wtrans_kernel<<<dim3(H_/32,  H_/32),  blk, 0, stream>>>(Wq, wt_qkv, H_, H_,  0);
    wtrans_kernel<<<dim3(512/32, H_/32),  blk, 0, stream>>>(Wk, wt_qkv, H_, 512, H_);
    wtrans_kernel<<<dim3(512/32, H_/32),  blk, 0, stream>>>(Wv, wt_qkv, H_, 512, H_ + 512);
    wtrans_kernel<<<dim3(H_/32,  H_/32),  blk, 0, stream>>>(Wo, wo_t,   H_, H_,  0);
    wtrans_kernel<<<dim3(FF_/32, H_/32),  blk, 0, stream>>>(W1, w1_t,   H_, FF_, 0);
    wtrans_kernel<<<dim3(H_/32,  FF_/32), blk, 0, stream>>>(W2, w2_t,   FF_, H_, 0);

    rmsnorm_kernel<<<dim3(TOK), blk, 0, stream>>>(hidden, g1, xn1);
    // QKV: grid 24x32 = 768 wg (3 blocks/CU)
    gemm5_kernel<0><<<dim3(QKVN/128, TOK/128), blk, 0, stream>>>(
        xn1, wt_qkv, bqkv, nullptr, qkv, TOK, QKVN, H_, H_);
    vtrans_kernel<<<dim3(TOK/32, HD_/32, NKV_), blk, 0, stream>>>(qkv, vt);
    attn_kernel<<<dim3(S_/64, NQ_, B_), blk, 0, stream>>>(qkv, vt, ctxb);
    // O-proj: +resid(hidden) -> x1 f32 ; grid 16x32 = 512 wg
    gemm5_kernel<2><<<dim3(H_/128, TOK/128), blk, 0, stream>>>(
        ctxb, wo_t, bo, hidden, x1, TOK, H_, H_, H_);
    rmsnorm_kernel<<<dim3(TOK), blk, 0, stream>>>(x1, g2, xn2);
    // FFN1: GELU -> ffn ; grid 64x32 = 2048 wg (8 blocks/CU queued)
    gemm5_kernel<1><<<dim3(FF_/128, TOK/128), blk, 0, stream>>>(
        xn2, w1_t, b1, nullptr, ffn, TOK, FF_, H_, H_);
    // FFN2: split-K=2 partials (bf16) ; grid 16x32x2 = 1024 wg
    gemm5_kernel<3><<<dim3(H_/128, TOK/128, 2), blk, 0, stream>>>(
        ffn, w2_t, nullptr, nullptr, fpart, TOK, H_, FF_, FF_/2);
    // reduce: out = p0 + p1 + b2 + x1
    reduce2_kernel<<<dim3(TOK*H_/(256*8)), blk, 0, stream>>>(fpart, b2, x1, out);
}

// Round 11
// 732.341 us; speedup vs baseline: 1.1073x; 1.1073x over previous
//
#include <hip/hip_runtime.h>
#include <cstdint>

// ---- problem constants ----
#define H_    2048
#define NQ_   16
#define NKV_  4
#define HD_   128
#define FF_   8192
#define B_    2
#define S_    2048
#define TOK   (B_*S_)            // 4096 tokens
#define QKVN  (H_ + 2*NKV_*HD_)  // 3072 = Q(2048) | K(512) | V(512)
#define KVB   64                 // attention KV tile

typedef __bf16 bf16;
typedef bf16  bf16x8 __attribute__((ext_vector_type(8)));
typedef float f32x4  __attribute__((ext_vector_type(4)));

typedef __attribute__((address_space(1))) void as1_void;
typedef __attribute__((address_space(3))) void as3_void;

__device__ __forceinline__ void gload_lds16(const void* g, void* l) {
    __builtin_amdgcn_global_load_lds((as1_void*)g, (as3_void*)l, 16, 0, 0);
}

// ======================================================================
// Weight convert + transpose: W[K][N] f32 -> Wt[outOff+N][K] bf16
// ======================================================================
__global__ __launch_bounds__(256) void wtrans_kernel(
    const float* __restrict__ W, bf16* __restrict__ Wt, int K, int N, int outOff)
{
    __shared__ float tile[32][33];
    const int n0 = (int)blockIdx.x * 32;
    const int k0 = (int)blockIdx.y * 32;
    const int c  = (int)threadIdx.x & 31;
    const int r  = (int)threadIdx.x >> 5;
#pragma unroll
    for (int i = 0; i < 4; ++i)
        tile[r + i*8][c] = W[(size_t)(k0 + r + i*8) * N + n0 + c];
    __syncthreads();
#pragma unroll
    for (int i = 0; i < 4; ++i)
        Wt[(size_t)(outOff + n0 + r + i*8) * K + k0 + c] = (bf16)tile[c][r + i*8];
}

__global__ void biaspack_kernel(const float* __restrict__ bq, const float* __restrict__ bk,
                                const float* __restrict__ bv, float* __restrict__ out)
{
    const int i = (int)(blockIdx.x * 256 + threadIdx.x);
    out[i] = (i < H_) ? bq[i] : (i < H_ + NKV_*HD_ ? bk[i - H_] : bv[i - H_ - NKV_*HD_]);
}

// ======================================================================
// RMSNorm: x f32 [rows][2048] -> y bf16
// ======================================================================
__global__ __launch_bounds__(256) void rmsnorm_kernel(
    const float* __restrict__ x, const float* __restrict__ g, bf16* __restrict__ y)
{
    const int row = (int)blockIdx.x;
    const int tid = (int)threadIdx.x;
    const float* xr = x + (size_t)row * H_;
    const float4 a = *(const float4*)(xr + tid*8);
    const float4 c = *(const float4*)(xr + tid*8 + 4);
    float ss = a.x*a.x + a.y*a.y + a.z*a.z + a.w*a.w
             + c.x*c.x + c.y*c.y + c.z*c.z + c.w*c.w;
#pragma unroll
    for (int d = 1; d < 64; d <<= 1) ss += __shfl_xor(ss, d);
    __shared__ float red[4];
    if ((tid & 63) == 0) red[tid >> 6] = ss;
    __syncthreads();
    const float inv = rsqrtf((red[0]+red[1]+red[2]+red[3]) * (1.0f/H_) + 1e-6f);
    const float vals[8] = {a.x,a.y,a.z,a.w,c.x,c.y,c.z,c.w};
    const float* gp = g + tid*8;
    bf16x8 outv;
#pragma unroll
    for (int e = 0; e < 8; ++e) outv[e] = (bf16)(vals[e] * inv * gp[e]);
    *(bf16x8*)(y + (size_t)row * H_ + tid*8) = outv;
}

// ======================================================================
// V transpose: qkv[tok][3072] V-slice -> Vt[(b*NKV+kh)*HD + d][S]
// ======================================================================
__global__ __launch_bounds__(256) void vtrans_kernel(
    const bf16* __restrict__ qkv, bf16* __restrict__ Vt)
{
    __shared__ bf16 tile[32][33];
    const int tt = (int)blockIdx.x;
    const int d0 = (int)blockIdx.y * 32;
    const int kh = (int)blockIdx.z;
    const int b  = (tt*32) / S_;
    const int s0 = (tt*32) % S_;
    const int c = (int)threadIdx.x & 31;
    const int r = (int)threadIdx.x >> 5;
#pragma unroll
    for (int i = 0; i < 4; ++i)
        tile[r + i*8][c] = qkv[(size_t)(tt*32 + r + i*8)*QKVN + H_ + NKV_*HD_ + kh*HD_ + d0 + c];
    __syncthreads();
#pragma unroll
    for (int i = 0; i < 4; ++i)
        Vt[((size_t)(b*NKV_ + kh)*HD_ + d0 + r + i*8)*S_ + s0 + c] = tile[c][r + i*8];
}

// ======================================================================
// GEMM v6 — round-3 kernel restored (best measured: 212us FFN1, 0 LDS
// read conflicts), with two low-risk additions:
//  (1) __launch_bounds__(256, 3): if the ~21% occupancy reading is real
//      (7 waves/CU despite resources for 16), reg-cap for >=3 waves/SIMD
//      adds TLP; if the counter was wrong, no-op.
//  (2) r8's XCD-chunk + 8m x 4n superblock mapping (proven correct,
//      FETCH 271->99MB) for L2 locality.
// Ledger from rounds 4-10: conflicts/schedule/shape/L2 all exonerated —
// m98's reference shows 1.7e7 conflicts at 874 TF, so the 1.26e7 reading
// was normal background. The 2-barrier structure is the best performer.
// MODE 0: +bias -> bf16. 1: GELU(v+bias) -> bf16. 2: v+bias+resid -> f32.
// ======================================================================
template<int MODE>
__global__ __launch_bounds__(256, 3) void gemm_kernel(
    const bf16* __restrict__ A, const bf16* __restrict__ Bt,
    const float* __restrict__ bias, const float* __restrict__ resid,
    void* __restrict__ Cout, int M, int N, int K)
{
    __shared__ bf16 lA[128*64];
    __shared__ bf16 lB[128*64];
    const int tid  = (int)threadIdx.x;
    const int wid  = tid >> 6;
    const int lane = tid & 63;
    const int lr   = lane & 15;
    const int lg   = lane >> 4;

    // ---- XCD chunk + 8m x 4n superblock of 32 wgs (L2 locality) ----
    const int gx  = (int)gridDim.x;            // N/128, mult of 4
    const int nwg = gx * (int)gridDim.y;       // mult of 32; nwg/8 mult of 32
    int wg = (int)blockIdx.y * gx + (int)blockIdx.x;
    wg = (wg & 7) * (nwg >> 3) + (wg >> 3);
    const int nsup  = gx >> 2;
    const int chunk = wg >> 5;
    const int cin   = wg & 31;
    const int m0 = ((chunk / nsup) * 8 + (cin >> 2)) * 128;
    const int n0 = ((chunk % nsup) * 4 + (cin & 3)) * 128;

    const int wm = (wid >> 1) * 64;
    const int wn = (wid & 1) * 64;

    f32x4 acc[4][4] = {};

    // staging: wave w covers rows [w*32, w*32+32); LDS[r][e]=src[r][e^(r&7)*8]
    const int sRow = wid*32 + (lane >> 3);
    const int sCol = ((lane & 7) ^ (lane >> 3)) * 8;
    const bf16* aSrc = A  + (size_t)(m0 + sRow) * K + sCol;
    const bf16* bSrc = Bt + (size_t)(n0 + sRow) * K + sCol;

    for (int k0 = 0; k0 < K; k0 += 64) {
#pragma unroll
        for (int i = 0; i < 4; ++i) {
            gload_lds16(aSrc + (size_t)(i*8)*K + k0, &lA[(wid*32 + i*8)*64]);
            gload_lds16(bSrc + (size_t)(i*8)*K + k0, &lB[(wid*32 + i*8)*64]);
        }
        __syncthreads();
#pragma unroll
        for (int kk = 0; kk < 64; kk += 32) {
            const int ks = (kk + lg*8) ^ ((lr & 7) * 8);
            bf16x8 af[4], bfr[4];
#pragma unroll
            for (int i = 0; i < 4; ++i)
                af[i] = *(const bf16x8*)&lA[(wm + i*16 + lr)*64 + ks];
#pragma unroll
            for (int j = 0; j < 4; ++j)
                bfr[j] = *(const bf16x8*)&lB[(wn + j*16 + lr)*64 + ks];
#pragma unroll
            for (int i = 0; i < 4; ++i)
#pragma unroll
                for (int j = 0; j < 4; ++j)
                    acc[i][j] = __builtin_amdgcn_mfma_f32_16x16x32_bf16(
                        af[i], bfr[j], acc[i][j], 0, 0, 0);
        }
        __syncthreads();
    }

#pragma unroll
    for (int j = 0; j < 4; ++j) {
        const int col = n0 + wn + j*16 + lr;
        const float bj = bias[col];
#pragma unroll
        for (int i = 0; i < 4; ++i) {
            const int row0 = m0 + wm + i*16 + lg*4;
#pragma unroll
            for (int rr = 0; rr < 4; ++rr) {
                float v = acc[i][j][rr] + bj;
                const size_t idx = (size_t)(row0 + rr) * N + col;
                if (MODE == 2) {
                    ((float*)Cout)[idx] = v + resid[idx];
                } else {
                    if (MODE == 1) v = 0.5f * v * (1.0f + erff(v * 0.70710678118654752f));
                    ((bf16*)Cout)[idx] = (bf16)v;
                }
            }
        }
    }
}

// ======================================================================
// Flash attention (causal, GQA rep=4). Grid (S/64, NQ, B), 256 thr.
// ======================================================================
__global__ __launch_bounds__(256) void attn_kernel(
    const bf16* __restrict__ qkv, const bf16* __restrict__ Vt,
    bf16* __restrict__ ctx)
{
    __shared__ bf16 lK[2][KVB*HD_];
    __shared__ bf16 lV[2][HD_*KVB];
    __shared__ bf16 lP[4][16*72];
    const int tid  = (int)threadIdx.x;
    const int wid  = tid >> 6;
    const int lane = tid & 63;
    const int lr   = lane & 15;
    const int lg   = lane >> 4;
    const int qt = (int)gridDim.x - 1 - (int)blockIdx.x;
    const int h = (int)blockIdx.y, b = (int)blockIdx.z;
    const int kh = h >> 2;
    const int qb = qt * 64;
    const int qw = qb + wid * 16;
    const float scale = 0.08838834764831845f;

    const bf16* kB[4];
    const bf16* vB[4];
#pragma unroll
    for (int i = 0; i < 4; ++i) {
        const int kRow = (wid*4 + i)*4 + (lane >> 4);
        const int kCol = ((lane & 15) ^ (kRow & 7)) * 8;
        kB[i] = qkv + (size_t)(b*S_ + kRow)*QKVN + H_ + kh*HD_ + kCol;
        const int vRow = (wid*4 + i)*8 + (lane >> 3);
        const int vCol = ((lane & 7) ^ (vRow & 7)) * 8;
        vB[i] = Vt + ((size_t)(b*NKV_ + kh)*HD_ + vRow)*S_ + vCol;
    }

    bf16x8 qf[4];
    {
        const bf16* qp = qkv + (size_t)(b*S_ + qw + lr)*QKVN + h*HD_ + lg*8;
#pragma unroll
        for (int t = 0; t < 4; ++t) qf[t] = *(const bf16x8*)(qp + t*32);
    }

    f32x4 o[8] = {};
    float mrow[4] = {-__builtin_inff(), -__builtin_inff(), -__builtin_inff(), -__builtin_inff()};
    float lrow[4] = {0.f, 0.f, 0.f, 0.f};
    const int nt = qt + 1;

#pragma unroll
    for (int i = 0; i < 4; ++i) {
        gload_lds16(kB[i], &lK[0][(wid*4 + i)*4*HD_]);
        gload_lds16(vB[i], &lV[0][(wid*4 + i)*8*KVB]);
    }

    int cur = 0;
    for (int t = 0; t < nt; ++t) {
        __syncthreads();
        if (t + 1 < nt) {
            const size_t kAdd = (size_t)(t+1)*KVB*QKVN;
            const size_t vAdd = (size_t)(t+1)*KVB;
#pragma unroll
            for (int i = 0; i < 4; ++i) {
                gload_lds16(kB[i] + kAdd, &lK[cur^1][(wid*4 + i)*4*HD_]);
                gload_lds16(vB[i] + vAdd, &lV[cur^1][(wid*4 + i)*8*KVB]);
            }
        }
        const int kv0 = t * KVB;

        f32x4 s[4] = {};
#pragma unroll
        for (int sub = 0; sub < 4; ++sub) {
            const int krow = sub*16 + lr;
            const bf16* kr = &lK[cur][krow*HD_];
            const int swk = (krow & 7) * 8;
#pragma unroll
            for (int d = 0; d < 4; ++d) {
                const bf16x8 kf = *(const bf16x8*)(kr + ((d*32 + lg*8) ^ swk));
                s[sub] = __builtin_amdgcn_mfma_f32_16x16x32_bf16(qf[d], kf, s[sub], 0, 0, 0);
            }
        }

        float p[4][4], rmax[4];
        if (t == qt) {
#pragma unroll
            for (int rr = 0; rr < 4; ++rr) {
                const int q = qw + lg*4 + rr;
                rmax[rr] = -__builtin_inff();
#pragma unroll
                for (int sub = 0; sub < 4; ++sub) {
                    const int kv = kv0 + sub*16 + lr;
                    const float v = s[sub][rr] * scale;
                    p[sub][rr] = (kv <= q) ? v : -__builtin_inff();
                    rmax[rr] = fmaxf(rmax[rr], p[sub][rr]);
                }
            }
        } else {
#pragma unroll
            for (int rr = 0; rr < 4; ++rr) {
                rmax[rr] = -__builtin_inff();
#pragma unroll
                for (int sub = 0; sub < 4; ++sub) {
                    p[sub][rr] = s[sub][rr] * scale;
                    rmax[rr] = fmaxf(rmax[rr], p[sub][rr]);
                }
            }
        }
#pragma unroll
        for (int d = 1; d < 16; d <<= 1)
#pragma unroll
            for (int rr = 0; rr < 4; ++rr)
                rmax[rr] = fmaxf(rmax[rr], __shfl_xor(rmax[rr], d));

        float fsc[4], rsum[4];
#pragma unroll
        for (int rr = 0; rr < 4; ++rr) {
            const float mn = fmaxf(mrow[rr], rmax[rr]);
            fsc[rr]  = __expf(mrow[rr] - mn);
            mrow[rr] = mn;
            rsum[rr] = 0.f;
#pragma unroll
            for (int sub = 0; sub < 4; ++sub) {
                p[sub][rr] = __expf(p[sub][rr] - mn);
                rsum[rr] += p[sub][rr];
            }
        }
#pragma unroll
        for (int d = 1; d < 16; d <<= 1)
#pragma unroll
            for (int rr = 0; rr < 4; ++rr)
                rsum[rr] += __shfl_xor(rsum[rr], d);
#pragma unroll
        for (int rr = 0; rr < 4; ++rr) lrow[rr] = lrow[rr]*fsc[rr] + rsum[rr];
#pragma unroll
        for (int dch = 0; dch < 8; ++dch)
#pragma unroll
            for (int rr = 0; rr < 4; ++rr) o[dch][rr] *= fsc[rr];

#pragma unroll
        for (int sub = 0; sub < 4; ++sub)
#pragma unroll
            for (int rr = 0; rr < 4; ++rr)
                lP[wid][(lg*4 + rr)*72 + sub*16 + lr] = (bf16)p[sub][rr];
        bf16x8 pfr[2];
#pragma unroll
        for (int kk = 0; kk < 2; ++kk)
            pfr[kk] = *(const bf16x8*)&lP[wid][lr*72 + kk*32 + lg*8];

#pragma unroll
        for (int dch = 0; dch < 8; ++dch) {
            const bf16* vr = &lV[cur][(dch*16 + lr)*KVB];
            const int swv = (lr & 7) * 8;
#pragma unroll
            for (int kk = 0; kk < 2; ++kk) {
                const bf16x8 vf = *(const bf16x8*)(vr + ((kk*32 + lg*8) ^ swv));
                o[dch] = __builtin_amdgcn_mfma_f32_16x16x32_bf16(pfr[kk], vf, o[dch], 0, 0, 0);
            }
        }
        cur ^= 1;
    }

#pragma unroll
    for (int rr = 0; rr < 4; ++rr) {
        const float inv = 1.0f / lrow[rr];
        bf16* cp = ctx + (size_t)(b*S_ + qw + lg*4 + rr) * H_ + h*HD_ + lr;
#pragma unroll
        for (int dch = 0; dch < 8; ++dch)
            cp[dch*16] = (bf16)(o[dch][rr] * inv);
    }
}

// ======================================================================
extern "C" void kernel_launch(void* const* d_in, const int* in_sizes, int n_in,
                              void* d_out, int out_size, void* d_ws, size_t ws_size,
                              hipStream_t stream)
{
    const float* hidden = (const float*)d_in[0];
    const float* Wq = (const float*)d_in[1];
    const float* bq = (const float*)d_in[2];
    const float* Wk = (const float*)d_in[3];
    const float* bk = (const float*)d_in[4];
    const float* Wv = (const float*)d_in[5];
    const float* bv = (const float*)d_in[6];
    const float* Wo = (const float*)d_in[7];
    const float* bo = (const float*)d_in[8];
    const float* W1 = (const float*)d_in[9];
    const float* b1 = (const float*)d_in[10];
    const float* W2 = (const float*)d_in[11];
    const float* b2 = (const float*)d_in[12];
    const float* g1 = (const float*)d_in[13];
    const float* g2 = (const float*)d_in[14];
    float* out = (float*)d_out;

    // d_ws is 256 MiB; vt aliases xn1 (dead after QKV GEMM).
    // Footprint = 264,253,440 B (proven fit).
    char* p = (char*)d_ws;
    auto alloc = [&](size_t bytes) { char* r = p; p += (bytes + 255) & ~(size_t)255; return r; };
    bf16*  wt_qkv = (bf16*)alloc((size_t)QKVN * H_ * 2);
    bf16*  wo_t   = (bf16*)alloc((size_t)H_ * H_ * 2);
    bf16*  w1_t   = (bf16*)alloc((size_t)FF_ * H_ * 2);
    bf16*  w2_t   = (bf16*)alloc((size_t)H_ * FF_ * 2);
    float* bqkv   = (float*)alloc((size_t)QKVN * 4);
    bf16*  xn1    = (bf16*)alloc((size_t)TOK * H_ * 2);
    bf16*  qkv    = (bf16*)alloc((size_t)TOK * QKVN * 2);
    bf16*  ctxb   = (bf16*)alloc((size_t)TOK * H_ * 2);
    float* x1     = (float*)alloc((size_t)TOK * H_ * 4);
    bf16*  xn2    = (bf16*)alloc((size_t)TOK * H_ * 2);
    bf16*  ffn    = (bf16*)alloc((size_t)TOK * FF_ * 2);
    bf16*  vt     = xn1;    // alias (xn1 dead after QKV GEMM)

    const dim3 blk(256);
    biaspack_kernel<<<dim3(QKVN/256), blk, 0, stream>>>(bq, bk, bv, bqkv);
    wtrans_kernel<<<dim3(H_/32,  H_/32),  blk, 0, stream>>>(Wq, wt_qkv, H_, H_,  0);
    wtrans_kernel<<<dim3(512/32, H_/32),  blk, 0, stream>>>(Wk, wt_qkv, H_, 512, H_);
    wtrans_kernel<<<dim3(512/32, H_/32),  blk, 0, stream>>>(Wv, wt_qkv, H_, 512, H_ + 512);
    wtrans_kernel<<<dim3(H_/32,  H_/32),  blk, 0, stream>>>(Wo, wo_t,   H_, H_,  0);
    wtrans_kernel<<<dim3(FF_/32, H_/32),  blk, 0, stream>>>(W1, w1_t,   H_, FF_, 0);
    wtrans_kernel<<<dim3(H_/32,  FF_/32), blk, 0, stream>>>(W2, w2_t,   FF_, H_, 0);

    rmsnorm_kernel<<<dim3(TOK), blk, 0, stream>>>(hidden, g1, xn1);
    // QKV: grid 24x32 = 768 wg
    gemm_kernel<0><<<dim3(QKVN/128, TOK/128), blk, 0, stream>>>(
        xn1, wt_qkv, bqkv, nullptr, qkv, TOK, QKVN, H_);
    vtrans_kernel<<<dim3(TOK/32, HD_/32, NKV_), blk, 0, stream>>>(qkv, vt);
    attn_kernel<<<dim3(S_/64, NQ_, B_), blk, 0, stream>>>(qkv, vt, ctxb);
    // O-proj: +resid(hidden) -> x1 f32 ; grid 16x32 = 512 wg
    gemm_kernel<2><<<dim3(H_/128, TOK/128), blk, 0, stream>>>(
        ctxb, wo_t, bo, hidden, x1, TOK, H_, H_);
    rmsnorm_kernel<<<dim3(TOK), blk, 0, stream>>>(x1, g2, xn2);
    // FFN1: GELU -> ffn ; grid 64x32 = 2048 wg
    gemm_kernel<1><<<dim3(FF_/128, TOK/128), blk, 0, stream>>>(
        xn2, w1_t, b1, nullptr, ffn, TOK, FF_, H_);
    // FFN2: direct, +resid(x1) -> out f32 ; grid 16x32 = 512 wg
    gemm_kernel<2><<<dim3(H_/128, TOK/128), blk, 0, stream>>>(
        ffn, w2_t, b2, x1, out, TOK, H_, FF_);
}